// Round 1
// baseline (1993.808 us; speedup 1.0000x reference)
//
#include <hip/hip_runtime.h>
#include <math.h>

#define T_TOK 8192
#define D_DIM 512
#define H_DIM 1024
#define NE    8

#define BM 32
#define BH 64

// ---------------- workspace layout (bytes) ----------------
// 0      : int   counts[8]      (== load per expert)
// 32     : float importance[8]
// 64     : int   offsets[8]
// 96     : int   cursor[8]
// 128    : int   top_e[T*2]
// 65664  : float top_p[T*2]
// 131200 : int   tok_list[T*2]
// 196736 : float gate_list[T*2]
// total 262272 B

// ---------------- gating: logits, top-2, softmax ----------------
__global__ __launch_bounds__(256) void gating_kernel(
    const float* __restrict__ x, const float* __restrict__ Wg,
    int* __restrict__ counts, float* __restrict__ importance,
    int* __restrict__ top_e, float* __restrict__ top_p)
{
  __shared__ float wgs[NE][D_DIM];   // transposed for conflict-free reads
  const int tid = threadIdx.x;
  for (int i = tid; i < D_DIM * NE; i += 256)
    wgs[i & 7][i >> 3] = Wg[i];
  __syncthreads();

  const int lane = tid & 63;
  const int wave = tid >> 6;
  const int t = blockIdx.x * 4 + wave;

  float acc[NE];
#pragma unroll
  for (int e = 0; e < NE; e++) acc[e] = 0.f;
#pragma unroll
  for (int j = 0; j < 8; j++) {
    const int d = lane + j * 64;
    const float xv = x[(size_t)t * D_DIM + d];
#pragma unroll
    for (int e = 0; e < NE; e++) acc[e] += xv * wgs[e][d];
  }
#pragma unroll
  for (int e = 0; e < NE; e++) {
#pragma unroll
    for (int m = 32; m > 0; m >>= 1) acc[e] += __shfl_xor(acc[e], m);
  }

  if (lane == 0) {
    // top-1 then top-2, strict > keeps lowest index on ties (jax semantics)
    int i0 = 0; float v0 = acc[0];
#pragma unroll
    for (int e = 1; e < NE; e++) if (acc[e] > v0) { v0 = acc[e]; i0 = e; }
    int i1 = -1; float v1 = -3.4e38f;
#pragma unroll
    for (int e = 0; e < NE; e++) if (e != i0 && acc[e] > v1) { v1 = acc[e]; i1 = e; }

    const float ex = __expf(v1 - v0);           // <= 1
    const float inv = 1.f / (1.f + ex);
    const float p0 = inv, p1 = ex * inv;

    top_e[t * 2 + 0] = i0; top_e[t * 2 + 1] = i1;
    top_p[t * 2 + 0] = p0; top_p[t * 2 + 1] = p1;
    atomicAdd(&counts[i0], 1);        atomicAdd(&counts[i1], 1);
    atomicAdd(&importance[i0], p0);   atomicAdd(&importance[i1], p1);
  }
}

// ---------------- finalize: offsets + losses ----------------
__global__ void finalize_kernel(const int* __restrict__ counts,
                                const float* __restrict__ importance,
                                int* __restrict__ offsets, int* __restrict__ cursor,
                                float* __restrict__ out_tail)
{
  if (threadIdx.x == 0) {
    int off = 0;
    float mi = 0.f, ml = 0.f;
    for (int e = 0; e < NE; e++) {
      offsets[e] = off; off += counts[e]; cursor[e] = 0;
      mi += importance[e]; ml += (float)counts[e];
    }
    mi *= (1.f / NE); ml *= (1.f / NE);
    float vi = 0.f, vl = 0.f;
    for (int e = 0; e < NE; e++) {
      const float di = importance[e] - mi; vi += di * di;
      const float dl = (float)counts[e] - ml; vl += dl * dl;
    }
    vi *= (1.f / (NE - 1)); vl *= (1.f / (NE - 1));   // ddof=1
    out_tail[0] = vi / (mi * mi + 1e-10f);
    out_tail[1] = vl / (ml * ml + 1e-10f);
  }
}

// ---------------- scatter tokens into expert buckets ----------------
__global__ __launch_bounds__(256) void scatter_kernel(
    const int* __restrict__ top_e, const float* __restrict__ top_p,
    const int* __restrict__ offsets, int* __restrict__ cursor,
    int* __restrict__ tok_list, float* __restrict__ gate_list)
{
  const int t = blockIdx.x * 256 + threadIdx.x;
#pragma unroll
  for (int k = 0; k < 2; k++) {
    const int e = top_e[t * 2 + k];
    const float p = top_p[t * 2 + k];
    const int pos = atomicAdd(&cursor[e], 1);
    const int slot = offsets[e] + pos;
    tok_list[slot] = t;
    gate_list[slot] = p;
  }
}

// ---------------- bucketed expert MLP: out += gate*(relu(xW1+b1)W2 + b2) ----------------
__global__ __launch_bounds__(256, 2) void moe_mlp_kernel(
    const float* __restrict__ x,
    const float* __restrict__ W1, const float* __restrict__ b1,
    const float* __restrict__ W2, const float* __restrict__ b2,
    const int* __restrict__ counts, const int* __restrict__ offsets,
    const int* __restrict__ tok_list, const float* __restrict__ gate_list,
    float* __restrict__ out)
{
  const int e    = blockIdx.x & 7;    // expert = bid%8 -> same expert lands on same XCD
  const int tile = blockIdx.x >> 3;
  const int cnt  = counts[e];
  if (tile * BM >= cnt) return;
  const int base = offsets[e] + tile * BM;

  __shared__ float Xs[BM][516];        // 66 KB, stride 2064B (16B aligned)
  __shared__ float Hs[BM][BH + 4];     // 8.7 KB, stride 272B (16B aligned)
  __shared__ int   tok_s[BM];
  __shared__ float gate_s[BM];

  const int tid = threadIdx.x;
  if (tid < BM) {
    const int gi = tile * BM + tid;
    if (gi < cnt) { tok_s[tid] = tok_list[base + tid]; gate_s[tid] = gate_list[base + tid]; }
    else          { tok_s[tid] = 0;                    gate_s[tid] = 0.f; }
  }
  __syncthreads();

  // gather 32 token rows of x into LDS (float4, coalesced)
#pragma unroll
  for (int i = 0; i < 16; i++) {
    const int idx = i * 256 + tid;
    const int r = idx >> 7;            // /128 float4 per row
    const int c4 = idx & 127;
    const float4 v = *reinterpret_cast<const float4*>(&x[(size_t)tok_s[r] * D_DIM + c4 * 4]);
    *reinterpret_cast<float4*>(&Xs[r][c4 * 4]) = v;
  }

  const float* __restrict__ W1e = W1 + (size_t)e * D_DIM * H_DIM;
  const float* __restrict__ W2e = W2 + (size_t)e * H_DIM * D_DIM;

  // stage-1 ownership: 2 rows x 4 h-cols per thread
  const int r0 = (tid >> 4) * 2;
  const int c0 = (tid & 15) * 4;
  // stage-2 ownership: 16 rows x 4 d-cols per thread
  const int r1 = (tid >> 7) * 16;
  const int c1 = (tid & 127) * 4;

  float acc[16][4];
#pragma unroll
  for (int r = 0; r < 16; r++)
#pragma unroll
    for (int j = 0; j < 4; j++) acc[r][j] = 0.f;

  __syncthreads();

  for (int hc = 0; hc < H_DIM; hc += BH) {
    // ---- stage 1: h[32][64] = relu(X @ W1[:, hc:hc+64] + b1) ----
    float h0[4], h1[4];
#pragma unroll
    for (int j = 0; j < 4; j++) {
      const float bv = b1[(size_t)e * H_DIM + hc + c0 + j];
      h0[j] = bv; h1[j] = bv;
    }
    for (int d = 0; d < D_DIM; d += 4) {
      const float4 xa4 = *reinterpret_cast<const float4*>(&Xs[r0][d]);
      const float4 xb4 = *reinterpret_cast<const float4*>(&Xs[r0 + 1][d]);
      const float xa[4] = {xa4.x, xa4.y, xa4.z, xa4.w};
      const float xb[4] = {xb4.x, xb4.y, xb4.z, xb4.w};
#pragma unroll
      for (int dd = 0; dd < 4; dd++) {
        const float4 w = *reinterpret_cast<const float4*>(&W1e[(size_t)(d + dd) * H_DIM + hc + c0]);
        h0[0] += xa[dd] * w.x; h0[1] += xa[dd] * w.y; h0[2] += xa[dd] * w.z; h0[3] += xa[dd] * w.w;
        h1[0] += xb[dd] * w.x; h1[1] += xb[dd] * w.y; h1[2] += xb[dd] * w.z; h1[3] += xb[dd] * w.w;
      }
    }
    *reinterpret_cast<float4*>(&Hs[r0][c0]) =
        make_float4(fmaxf(h0[0], 0.f), fmaxf(h0[1], 0.f), fmaxf(h0[2], 0.f), fmaxf(h0[3], 0.f));
    *reinterpret_cast<float4*>(&Hs[r0 + 1][c0]) =
        make_float4(fmaxf(h1[0], 0.f), fmaxf(h1[1], 0.f), fmaxf(h1[2], 0.f), fmaxf(h1[3], 0.f));
    __syncthreads();

    // ---- stage 2: acc[32][512] += h @ W2[hc:hc+64, :] ----
    for (int k = 0; k < BH; k += 4) {
      float4 w[4];
#pragma unroll
      for (int kk = 0; kk < 4; kk++)
        w[kk] = *reinterpret_cast<const float4*>(&W2e[(size_t)(hc + k + kk) * D_DIM + c1]);
#pragma unroll
      for (int r = 0; r < 16; r++) {
        const float4 h4 = *reinterpret_cast<const float4*>(&Hs[r1 + r][k]);  // broadcast read
        acc[r][0] += h4.x * w[0].x + h4.y * w[1].x + h4.z * w[2].x + h4.w * w[3].x;
        acc[r][1] += h4.x * w[0].y + h4.y * w[1].y + h4.z * w[2].y + h4.w * w[3].y;
        acc[r][2] += h4.x * w[0].z + h4.y * w[1].z + h4.z * w[2].z + h4.w * w[3].z;
        acc[r][3] += h4.x * w[0].w + h4.y * w[1].w + h4.z * w[2].w + h4.w * w[3].w;
      }
    }
    __syncthreads();   // protect Hs before next chunk's stage-1 writes
  }

  // ---- epilogue: out[t] += gate * (acc + b2) ----
  float b2v[4];
#pragma unroll
  for (int j = 0; j < 4; j++) b2v[j] = b2[(size_t)e * D_DIM + c1 + j];
#pragma unroll
  for (int r = 0; r < 16; r++) {
    const int row = r1 + r;
    const float p = gate_s[row];
    float* op = &out[(size_t)tok_s[row] * D_DIM + c1];
#pragma unroll
    for (int j = 0; j < 4; j++)
      atomicAdd(&op[j], p * (acc[r][j] + b2v[j]));
  }
}

// ---------------- launcher ----------------
extern "C" void kernel_launch(void* const* d_in, const int* in_sizes, int n_in,
                              void* d_out, int out_size, void* d_ws, size_t ws_size,
                              hipStream_t stream)
{
  const float* x  = (const float*)d_in[0];
  const float* Wg = (const float*)d_in[1];
  const float* W1 = (const float*)d_in[2];
  const float* b1 = (const float*)d_in[3];
  const float* W2 = (const float*)d_in[4];
  const float* b2 = (const float*)d_in[5];
  float* out = (float*)d_out;

  char* ws = (char*)d_ws;
  int*   counts     = (int*)(ws + 0);
  float* importance = (float*)(ws + 32);
  int*   offsets    = (int*)(ws + 64);
  int*   cursor     = (int*)(ws + 96);
  int*   top_e      = (int*)(ws + 128);
  float* top_p      = (float*)(ws + 128 + 65536);
  int*   tok_list   = (int*)(ws + 128 + 131072);
  float* gate_list  = (float*)(ws + 128 + 196608);

  // zero accumulators (ws/out are poisoned 0xAA before every launch)
  hipMemsetAsync(d_ws, 0, 128, stream);
  hipMemsetAsync(d_out, 0, (size_t)T_TOK * D_DIM * sizeof(float), stream);

  gating_kernel<<<T_TOK / 4, 256, 0, stream>>>(x, Wg, counts, importance, top_e, top_p);
  finalize_kernel<<<1, 64, 0, stream>>>(counts, importance, offsets, cursor,
                                        out + (size_t)T_TOK * D_DIM);
  scatter_kernel<<<T_TOK / 256, 256, 0, stream>>>(top_e, top_p, offsets, cursor,
                                                  tok_list, gate_list);
  moe_mlp_kernel<<<(T_TOK / BM) * NE, 256, 0, stream>>>(
      x, W1, b1, W2, b2, counts, offsets, tok_list, gate_list, out);
}

// Round 3
// 781.511 us; speedup vs baseline: 2.5512x; 2.5512x over previous
//
#include <hip/hip_runtime.h>
#include <math.h>

#define T_TOK 8192
#define D_DIM 512
#define H_DIM 1024
#define NE    8

typedef __attribute__((ext_vector_type(8))) short bf16x8;
typedef __attribute__((ext_vector_type(4))) float f32x4;
typedef __attribute__((ext_vector_type(4))) unsigned short us4;
typedef __attribute__((ext_vector_type(8))) unsigned short us8;

// ---------------- workspace layout (bytes) ----------------
// 0       counts[8] | 32 importance[8] | 64 offsets[8] | 96 cursor[8]
// 128     top_e[16384] int      (64 KB)
// 65664   top_p[16384] float    (64 KB)
// 131200  tok_list[16384] int
// 196736  gate_list[16384] float
// 1 MB    XB   bf16 [8192][512]      8 MB
// 9 MB    W1T  bf16 [8][1024][512]   8 MB   (W1 transposed: [e][h][d])
// 17 MB   W2T  bf16 [8][512][1024]   8 MB   (W2 transposed: [e][d][h])
// 25 MB   HBUF bf16 [16384][1024]   32 MB   (per-slot hidden activations)
// total 57 MB

__device__ __forceinline__ unsigned short f2bf(float f) {
  union { float f; unsigned int u; } v; v.f = f;
  const unsigned int u = v.u;
  return (unsigned short)((u + 0x7fffu + ((u >> 16) & 1u)) >> 16);  // RNE
}

__device__ __forceinline__ void gload16(const void* g, void* l) {
  __builtin_amdgcn_global_load_lds(
      (const __attribute__((address_space(1))) void*)g,
      (__attribute__((address_space(3))) void*)l, 16, 0, 0);
}

// ---------------- x -> bf16 ----------------
__global__ __launch_bounds__(256) void cvt_x_kernel(const float* __restrict__ x,
                                                    unsigned short* __restrict__ xb) {
  const int i = (blockIdx.x * 256 + threadIdx.x) * 8;
  const float4 a = *reinterpret_cast<const float4*>(&x[i]);
  const float4 b = *reinterpret_cast<const float4*>(&x[i + 4]);
  us8 o;
  o[0] = f2bf(a.x); o[1] = f2bf(a.y); o[2] = f2bf(a.z); o[3] = f2bf(a.w);
  o[4] = f2bf(b.x); o[5] = f2bf(b.y); o[6] = f2bf(b.z); o[7] = f2bf(b.w);
  *reinterpret_cast<us8*>(&xb[i]) = o;
}

// ---------------- W1/W2 -> bf16, transposed per expert ----------------
__global__ __launch_bounds__(256) void wtrans_kernel(
    const float* __restrict__ W1, const float* __restrict__ W2,
    unsigned short* __restrict__ W1T, unsigned short* __restrict__ W2T) {
  __shared__ unsigned short lds[32][36];
  int bid = blockIdx.x;
  const float* src; unsigned short* dst; int R, C, lc;
  if (bid < 4096) { src = W1; dst = W1T; R = D_DIM; C = H_DIM; lc = 5; }
  else { bid -= 4096; src = W2; dst = W2T; R = H_DIM; C = D_DIM; lc = 4; }
  const int e = bid >> 9;                 // 512 tiles per expert (both matrices)
  const int rem = bid & 511;
  const int rt = rem >> lc;
  const int ct = rem & ((C >> 5) - 1);
  const size_t ebase = (size_t)e * R * C;
  const int tid = threadIdx.x;
  {
    const int r = tid >> 3, c0 = (tid & 7) * 4;
    const float4 v = *reinterpret_cast<const float4*>(
        &src[ebase + (size_t)(rt * 32 + r) * C + ct * 32 + c0]);
    lds[r][c0 + 0] = f2bf(v.x); lds[r][c0 + 1] = f2bf(v.y);
    lds[r][c0 + 2] = f2bf(v.z); lds[r][c0 + 3] = f2bf(v.w);
  }
  __syncthreads();
  {
    const int c = tid >> 3, r0 = (tid & 7) * 4;
    us4 o;
    o[0] = lds[r0 + 0][c]; o[1] = lds[r0 + 1][c];
    o[2] = lds[r0 + 2][c]; o[3] = lds[r0 + 3][c];
    *reinterpret_cast<us4*>(&dst[ebase + (size_t)(ct * 32 + c) * R + rt * 32 + r0]) = o;
  }
}

// ---------------- gating: logits, top-2, softmax ----------------
__global__ __launch_bounds__(256) void gating_kernel(
    const float* __restrict__ x, const float* __restrict__ Wg,
    int* __restrict__ counts, float* __restrict__ importance,
    int* __restrict__ top_e, float* __restrict__ top_p)
{
  __shared__ float wgs[NE][D_DIM];
  const int tid = threadIdx.x;
  for (int i = tid; i < D_DIM * NE; i += 256)
    wgs[i & 7][i >> 3] = Wg[i];
  __syncthreads();

  const int lane = tid & 63;
  const int wave = tid >> 6;
  const int t = blockIdx.x * 4 + wave;

  float acc[NE];
#pragma unroll
  for (int e = 0; e < NE; e++) acc[e] = 0.f;
#pragma unroll
  for (int j = 0; j < 8; j++) {
    const int d = lane + j * 64;
    const float xv = x[(size_t)t * D_DIM + d];
#pragma unroll
    for (int e = 0; e < NE; e++) acc[e] += xv * wgs[e][d];
  }
#pragma unroll
  for (int e = 0; e < NE; e++) {
#pragma unroll
    for (int m = 32; m > 0; m >>= 1) acc[e] += __shfl_xor(acc[e], m);
  }

  if (lane == 0) {
    int i0 = 0; float v0 = acc[0];
#pragma unroll
    for (int e = 1; e < NE; e++) if (acc[e] > v0) { v0 = acc[e]; i0 = e; }
    int i1 = -1; float v1 = -3.4e38f;
#pragma unroll
    for (int e = 0; e < NE; e++) if (e != i0 && acc[e] > v1) { v1 = acc[e]; i1 = e; }

    const float ex = __expf(v1 - v0);
    const float inv = 1.f / (1.f + ex);
    const float p0 = inv, p1 = ex * inv;

    top_e[t * 2 + 0] = i0; top_e[t * 2 + 1] = i1;
    top_p[t * 2 + 0] = p0; top_p[t * 2 + 1] = p1;
    atomicAdd(&counts[i0], 1);      atomicAdd(&counts[i1], 1);
    atomicAdd(&importance[i0], p0); atomicAdd(&importance[i1], p1);
  }
}

// ---------------- finalize: offsets + losses ----------------
__global__ void finalize_kernel(const int* __restrict__ counts,
                                const float* __restrict__ importance,
                                int* __restrict__ offsets, int* __restrict__ cursor,
                                float* __restrict__ out_tail)
{
  if (threadIdx.x == 0) {
    int off = 0;
    float mi = 0.f, ml = 0.f;
    for (int e = 0; e < NE; e++) {
      offsets[e] = off; off += counts[e]; cursor[e] = 0;
      mi += importance[e]; ml += (float)counts[e];
    }
    mi *= (1.f / NE); ml *= (1.f / NE);
    float vi = 0.f, vl = 0.f;
    for (int e = 0; e < NE; e++) {
      const float di = importance[e] - mi; vi += di * di;
      const float dl = (float)counts[e] - ml; vl += dl * dl;
    }
    vi *= (1.f / (NE - 1)); vl *= (1.f / (NE - 1));
    out_tail[0] = vi / (mi * mi + 1e-10f);
    out_tail[1] = vl / (ml * ml + 1e-10f);
  }
}

// ---------------- scatter tokens into expert buckets ----------------
__global__ __launch_bounds__(256) void scatter_kernel(
    const int* __restrict__ top_e, const float* __restrict__ top_p,
    const int* __restrict__ offsets, int* __restrict__ cursor,
    int* __restrict__ tok_list, float* __restrict__ gate_list)
{
  const int t = blockIdx.x * 256 + threadIdx.x;
#pragma unroll
  for (int k = 0; k < 2; k++) {
    const int e = top_e[t * 2 + k];
    const float p = top_p[t * 2 + k];
    const int pos = atomicAdd(&cursor[e], 1);
    const int slot = offsets[e] + pos;
    tok_list[slot] = t;
    gate_list[slot] = p;
  }
}

// ---------------- MFMA expert GEMM (both stages) ----------------
// Computes C[m=weight-dim][n=token] = Wt_tile(128 x KD) . Bsrc_tile(KD x 128)
// Wt is [NE][M][KD] bf16 (pre-transposed), Bsrc rows are KD-contiguous bf16.
// STAGE2=false: Hout[slot][h] = relu(C + b1), bf16.
// STAGE2=true : out[tok][d] += gate * (C + b2), f32 atomics.
template<int KD, int MTILES, bool STAGE2>
__global__ __launch_bounds__(256) void expert_gemm_kernel(
    const unsigned short* __restrict__ Wt,
    const unsigned short* __restrict__ Bsrc,
    const float* __restrict__ bias,
    const int* __restrict__ counts, const int* __restrict__ offsets,
    const int* __restrict__ tok_list, const float* __restrict__ gate_list,
    unsigned short* __restrict__ Hout, float* __restrict__ out)
{
  constexpr int M = MTILES * 128;
  constexpr int LMT = (MTILES == 8) ? 3 : 2;
  const int e = blockIdx.x & 7;          // expert on fixed XCD -> weight L2 residency
  const int tmp = blockIdx.x >> 3;
  const int mtile = tmp & (MTILES - 1);
  const int ttile = tmp >> LMT;
  const int cnt = counts[e];
  if (ttile * 128 >= cnt) return;
  const int base = offsets[e] + ttile * 128;
  const int rem = cnt - ttile * 128;
  const int nvalid = rem < 128 ? rem : 128;

  __shared__ unsigned short Ws[128][64];   // weight tile  [m][k], XOR-slot swizzled
  __shared__ unsigned short Xs[128][64];   // token tile   [n][k], XOR-slot swizzled

  const int tid = threadIdx.x;
  const int lane = tid & 63;
  const int wave = tid >> 6;
  const int wm = wave & 1, wn = wave >> 1;

  // staging sources: 4 x 16B segs per thread per buffer; LDS dest linear,
  // swizzle applied on the GLOBAL column (both-sides involution, T2/m201)
  const unsigned short* wsrc[4];
  const unsigned short* bsrc[4];
#pragma unroll
  for (int i = 0; i < 4; i++) {
    const int seg = tid + i * 256;
    const int row = seg >> 3;
    const int s = seg & 7;
    const int scol = ((s ^ (row & 7)) << 3);
    wsrc[i] = Wt + ((size_t)e * M + (size_t)(mtile * 128 + row)) * KD + scol;
    const int cr = (row < nvalid) ? row : (nvalid - 1);
    const int brow = STAGE2 ? (base + cr) : tok_list[base + cr];
    bsrc[i] = Bsrc + (size_t)brow * KD + scol;
  }
  unsigned short* ws0 = &Ws[0][0];
  unsigned short* xs0 = &Xs[0][0];
  const int ldso = wave * 512;   // ushort elems; HW adds lane*16B

  f32x4 acc[4][4];
#pragma unroll
  for (int mi = 0; mi < 4; mi++)
#pragma unroll
    for (int nj = 0; nj < 4; nj++)
#pragma unroll
      for (int q = 0; q < 4; q++) acc[mi][nj][q] = 0.f;

  for (int k0 = 0; k0 < KD; k0 += 64) {
#pragma unroll
    for (int i = 0; i < 4; i++) {
      gload16(wsrc[i] + k0, ws0 + ldso + i * 2048);
      gload16(bsrc[i] + k0, xs0 + ldso + i * 2048);
    }
    __syncthreads();   // drains vmcnt before barrier -> tiles ready
#pragma unroll
    for (int ks = 0; ks < 2; ks++) {
      bf16x8 a[4], b[4];
#pragma unroll
      for (int mi = 0; mi < 4; mi++) {
        const int m = wm * 64 + mi * 16 + (lane & 15);
        const int sl = ((ks * 4 + (lane >> 4)) ^ (m & 7)) << 3;
        a[mi] = *reinterpret_cast<const bf16x8*>(&Ws[m][sl]);
      }
#pragma unroll
      for (int nj = 0; nj < 4; nj++) {
        const int r = wn * 64 + nj * 16 + (lane & 15);
        const int sl = ((ks * 4 + (lane >> 4)) ^ (r & 7)) << 3;
        b[nj] = *reinterpret_cast<const bf16x8*>(&Xs[r][sl]);
      }
#pragma unroll
      for (int mi = 0; mi < 4; mi++)
#pragma unroll
        for (int nj = 0; nj < 4; nj++)
          acc[mi][nj] = __builtin_amdgcn_mfma_f32_16x16x32_bf16(a[mi], b[nj], acc[mi][nj], 0, 0, 0);
    }
    __syncthreads();
  }

  // epilogue: C elem (mi,nj,j): m_loc = wm*64+mi*16+(lane>>4)*4+j (weight dim),
  //                             n_loc = wn*64+nj*16+(lane&15)     (token slot)
  if (!STAGE2) {
#pragma unroll
    for (int mi = 0; mi < 4; mi++) {
      const int mb = mtile * 128 + wm * 64 + mi * 16 + ((lane >> 4) << 2);
      float bv[4];
#pragma unroll
      for (int j = 0; j < 4; j++) bv[j] = bias[e * M + mb + j];
#pragma unroll
      for (int nj = 0; nj < 4; nj++) {
        const int r = wn * 64 + nj * 16 + (lane & 15);
        if (r < nvalid) {
          us4 o;
#pragma unroll
          for (int j = 0; j < 4; j++)
            o[j] = f2bf(fmaxf(acc[mi][nj][j] + bv[j], 0.f));
          *reinterpret_cast<us4*>(&Hout[(size_t)(base + r) * H_DIM + mb]) = o;
        }
      }
    }
  } else {
    float bv[4][4];
    int dbs[4];
#pragma unroll
    for (int mi = 0; mi < 4; mi++) {
      dbs[mi] = mtile * 128 + wm * 64 + mi * 16 + ((lane >> 4) << 2);
#pragma unroll
      for (int j = 0; j < 4; j++) bv[mi][j] = bias[e * M + dbs[mi] + j];
    }
#pragma unroll
    for (int nj = 0; nj < 4; nj++) {
      const int r = wn * 64 + nj * 16 + (lane & 15);
      if (r >= nvalid) continue;
      const int slot = base + r;
      const int tok = tok_list[slot];
      const float g = gate_list[slot];
      float* orow = out + (size_t)tok * D_DIM;
#pragma unroll
      for (int mi = 0; mi < 4; mi++)
#pragma unroll
        for (int j = 0; j < 4; j++)
          atomicAdd(&orow[dbs[mi] + j], (acc[mi][nj][j] + bv[mi][j]) * g);
    }
  }
}

// ---------------- launcher ----------------
extern "C" void kernel_launch(void* const* d_in, const int* in_sizes, int n_in,
                              void* d_out, int out_size, void* d_ws, size_t ws_size,
                              hipStream_t stream)
{
  const float* x  = (const float*)d_in[0];
  const float* Wg = (const float*)d_in[1];
  const float* W1 = (const float*)d_in[2];
  const float* b1 = (const float*)d_in[3];
  const float* W2 = (const float*)d_in[4];
  const float* b2 = (const float*)d_in[5];
  float* out = (float*)d_out;

  char* ws = (char*)d_ws;
  int*   counts     = (int*)(ws + 0);
  float* importance = (float*)(ws + 32);
  int*   offsets    = (int*)(ws + 64);
  int*   cursor     = (int*)(ws + 96);
  int*   top_e      = (int*)(ws + 128);
  float* top_p      = (float*)(ws + 128 + 65536);
  int*   tok_list   = (int*)(ws + 128 + 131072);
  float* gate_list  = (float*)(ws + 128 + 196608);
  unsigned short* XB   = (unsigned short*)(ws + (1ull << 20));
  unsigned short* W1T  = (unsigned short*)(ws + (9ull << 20));
  unsigned short* W2T  = (unsigned short*)(ws + (17ull << 20));
  unsigned short* HBUF = (unsigned short*)(ws + (25ull << 20));

  hipMemsetAsync(d_ws, 0, 128, stream);
  hipMemsetAsync(d_out, 0, (size_t)T_TOK * D_DIM * sizeof(float), stream);

  cvt_x_kernel<<<2048, 256, 0, stream>>>(x, XB);
  wtrans_kernel<<<8192, 256, 0, stream>>>(W1, W2, W1T, W2T);
  gating_kernel<<<T_TOK / 4, 256, 0, stream>>>(x, Wg, counts, importance, top_e, top_p);
  finalize_kernel<<<1, 64, 0, stream>>>(counts, importance, offsets, cursor,
                                        out + (size_t)T_TOK * D_DIM);
  scatter_kernel<<<T_TOK / 256, 256, 0, stream>>>(top_e, top_p, offsets, cursor,
                                                  tok_list, gate_list);
  // stage 1: H = relu(x @ W1 + b1)   (M=1024, K=512)
  expert_gemm_kernel<512, 8, false><<<8 * 8 * 64, 256, 0, stream>>>(
      W1T, XB, b1, counts, offsets, tok_list, gate_list, HBUF, nullptr);
  // stage 2: out += gate * (H @ W2 + b2)   (M=512, K=1024)
  expert_gemm_kernel<1024, 4, true><<<8 * 4 * 64, 256, 0, stream>>>(
      W2T, HBUF, b2, counts, offsets, tok_list, gate_list, nullptr, out);
}

// Round 4
// 302.460 us; speedup vs baseline: 6.5920x; 2.5839x over previous
//
#include <hip/hip_runtime.h>
#include <math.h>

#define T_TOK 8192
#define D_DIM 512
#define H_DIM 1024
#define NE    8
#define NHB   64    // histogram/scatter blocks (64 x 256 threads = 16384 entries)

typedef __attribute__((ext_vector_type(8))) short bf16x8;
typedef __attribute__((ext_vector_type(4))) float f32x4;
typedef __attribute__((ext_vector_type(4))) unsigned short us4;
typedef __attribute__((ext_vector_type(8))) unsigned short us8;

// ---------------- workspace layout (bytes) ----------------
// 0       counts[8] | 32 importance[8] | 64 offsets[8]
// 128     top_e[16384] int      (64 KB)
// 65664   top_p[16384] float    (64 KB)
// 131200  tok_list[16384] int
// 196736  gate_list[16384] float
// 262400  hist[64][8] int   (2 KB)
// 264448  impp[64][8] float (2 KB)
// 266496  bb[64][8] int     (2 KB)
// 1 MB    XB   bf16 [8192][512]      8 MB
// 9 MB    W1T  bf16 [8][1024][512]   8 MB
// 17 MB   W2T  bf16 [8][512][1024]   8 MB
// 25 MB   HBUF bf16 [16384][1024]   32 MB

__device__ __forceinline__ unsigned short f2bf(float f) {
  union { float f; unsigned int u; } v; v.f = f;
  const unsigned int u = v.u;
  return (unsigned short)((u + 0x7fffu + ((u >> 16) & 1u)) >> 16);  // RNE
}

__device__ __forceinline__ void gload16(const void* g, void* l) {
  __builtin_amdgcn_global_load_lds(
      (const __attribute__((address_space(1))) void*)g,
      (__attribute__((address_space(3))) void*)l, 16, 0, 0);
}

// ---------------- x -> bf16 ----------------
__global__ __launch_bounds__(256) void cvt_x_kernel(const float* __restrict__ x,
                                                    unsigned short* __restrict__ xb) {
  const int i = (blockIdx.x * 256 + threadIdx.x) * 8;
  const float4 a = *reinterpret_cast<const float4*>(&x[i]);
  const float4 b = *reinterpret_cast<const float4*>(&x[i + 4]);
  us8 o;
  o[0] = f2bf(a.x); o[1] = f2bf(a.y); o[2] = f2bf(a.z); o[3] = f2bf(a.w);
  o[4] = f2bf(b.x); o[5] = f2bf(b.y); o[6] = f2bf(b.z); o[7] = f2bf(b.w);
  *reinterpret_cast<us8*>(&xb[i]) = o;
}

// ---------------- W1/W2 -> bf16, transposed per expert ----------------
__global__ __launch_bounds__(256) void wtrans_kernel(
    const float* __restrict__ W1, const float* __restrict__ W2,
    unsigned short* __restrict__ W1T, unsigned short* __restrict__ W2T) {
  __shared__ unsigned short lds[32][36];
  int bid = blockIdx.x;
  const float* src; unsigned short* dst; int R, C, lc;
  if (bid < 4096) { src = W1; dst = W1T; R = D_DIM; C = H_DIM; lc = 5; }
  else { bid -= 4096; src = W2; dst = W2T; R = H_DIM; C = D_DIM; lc = 4; }
  const int e = bid >> 9;
  const int rem = bid & 511;
  const int rt = rem >> lc;
  const int ct = rem & ((C >> 5) - 1);
  const size_t ebase = (size_t)e * R * C;
  const int tid = threadIdx.x;
  {
    const int r = tid >> 3, c0 = (tid & 7) * 4;
    const float4 v = *reinterpret_cast<const float4*>(
        &src[ebase + (size_t)(rt * 32 + r) * C + ct * 32 + c0]);
    lds[r][c0 + 0] = f2bf(v.x); lds[r][c0 + 1] = f2bf(v.y);
    lds[r][c0 + 2] = f2bf(v.z); lds[r][c0 + 3] = f2bf(v.w);
  }
  __syncthreads();
  {
    const int c = tid >> 3, r0 = (tid & 7) * 4;
    us4 o;
    o[0] = lds[r0 + 0][c]; o[1] = lds[r0 + 1][c];
    o[2] = lds[r0 + 2][c]; o[3] = lds[r0 + 3][c];
    *reinterpret_cast<us4*>(&dst[ebase + (size_t)(ct * 32 + c) * R + rt * 32 + r0]) = o;
  }
}

// ---------------- gating: logits, top-2, softmax (NO global atomics) ----------------
__global__ __launch_bounds__(256) void gating_kernel(
    const float* __restrict__ x, const float* __restrict__ Wg,
    int* __restrict__ top_e, float* __restrict__ top_p)
{
  __shared__ float wgs[NE][D_DIM];
  const int tid = threadIdx.x;
  for (int i = tid; i < D_DIM * NE; i += 256)
    wgs[i & 7][i >> 3] = Wg[i];
  __syncthreads();

  const int lane = tid & 63;
  const int wave = tid >> 6;
  const int t = blockIdx.x * 4 + wave;

  float acc[NE];
#pragma unroll
  for (int e = 0; e < NE; e++) acc[e] = 0.f;
#pragma unroll
  for (int j = 0; j < 8; j++) {
    const int d = lane + j * 64;
    const float xv = x[(size_t)t * D_DIM + d];
#pragma unroll
    for (int e = 0; e < NE; e++) acc[e] += xv * wgs[e][d];
  }
#pragma unroll
  for (int e = 0; e < NE; e++) {
#pragma unroll
    for (int m = 32; m > 0; m >>= 1) acc[e] += __shfl_xor(acc[e], m);
  }

  if (lane == 0) {
    int i0 = 0; float v0 = acc[0];
#pragma unroll
    for (int e = 1; e < NE; e++) if (acc[e] > v0) { v0 = acc[e]; i0 = e; }
    int i1 = -1; float v1 = -3.4e38f;
#pragma unroll
    for (int e = 0; e < NE; e++) if (e != i0 && acc[e] > v1) { v1 = acc[e]; i1 = e; }

    const float ex = __expf(v1 - v0);
    const float inv = 1.f / (1.f + ex);
    top_e[t * 2 + 0] = i0; top_e[t * 2 + 1] = i1;
    top_p[t * 2 + 0] = inv; top_p[t * 2 + 1] = ex * inv;
  }
}

// ---------------- per-block histogram + importance partials (LDS atomics only) ----------------
__global__ __launch_bounds__(256) void hist_kernel(
    const int* __restrict__ top_e, const float* __restrict__ top_p,
    int* __restrict__ hist, float* __restrict__ impp)
{
  __shared__ int   h[NE];
  __shared__ float im[NE];
  const int tid = threadIdx.x;
  if (tid < NE) { h[tid] = 0; im[tid] = 0.f; }
  __syncthreads();
  const int i = blockIdx.x * 256 + tid;
  const int e = top_e[i];
  atomicAdd(&h[e], 1);
  atomicAdd(&im[e], top_p[i]);
  __syncthreads();
  if (tid < NE) {
    hist[blockIdx.x * NE + tid] = h[tid];
    impp[blockIdx.x * NE + tid] = im[tid];
  }
}

// ---------------- finalize: counts/offsets/block-bases + losses ----------------
__global__ void finalize_kernel(const int* __restrict__ hist,
                                const float* __restrict__ impp,
                                int* __restrict__ counts, float* __restrict__ importance,
                                int* __restrict__ offsets, int* __restrict__ bb,
                                float* __restrict__ out_tail)
{
  __shared__ int   cnt_s[NE];
  __shared__ float imp_s[NE];
  __shared__ int   off_s[NE];
  const int tid = threadIdx.x;
  if (tid < NE) {                       // one thread per expert
    int c = 0; float s = 0.f;
    for (int b = 0; b < NHB; b++) { c += hist[b * NE + tid]; s += impp[b * NE + tid]; }
    cnt_s[tid] = c; imp_s[tid] = s;
    counts[tid] = c; importance[tid] = s;
  }
  __syncthreads();
  if (tid == 0) {
    int off = 0;
    for (int e = 0; e < NE; e++) { off_s[e] = off; offsets[e] = off; off += cnt_s[e]; }
    float mi = 0.f, ml = 0.f;
    for (int e = 0; e < NE; e++) { mi += imp_s[e]; ml += (float)cnt_s[e]; }
    mi *= (1.f / NE); ml *= (1.f / NE);
    float vi = 0.f, vl = 0.f;
    for (int e = 0; e < NE; e++) {
      const float di = imp_s[e] - mi; vi += di * di;
      const float dl = (float)cnt_s[e] - ml; vl += dl * dl;
    }
    vi *= (1.f / (NE - 1)); vl *= (1.f / (NE - 1));   // ddof=1
    out_tail[0] = vi / (mi * mi + 1e-10f);
    out_tail[1] = vl / (ml * ml + 1e-10f);
  }
  __syncthreads();
  if (tid < NE) {                       // running base per expert across blocks
    int run = off_s[tid];
    for (int b = 0; b < NHB; b++) { bb[b * NE + tid] = run; run += hist[b * NE + tid]; }
  }
}

// ---------------- scatter: slot assignment via LDS cursors ----------------
__global__ __launch_bounds__(256) void scatter_kernel(
    const int* __restrict__ top_e, const float* __restrict__ top_p,
    const int* __restrict__ bb,
    int* __restrict__ tok_list, float* __restrict__ gate_list)
{
  __shared__ int cur[NE];
  const int tid = threadIdx.x;
  if (tid < NE) cur[tid] = bb[blockIdx.x * NE + tid];
  __syncthreads();
  const int i = blockIdx.x * 256 + tid;
  const int e = top_e[i];
  const int pos = atomicAdd(&cur[e], 1);   // LDS atomic: intra-block only
  tok_list[pos] = i >> 1;
  gate_list[pos] = top_p[i];
}

// ---------------- MFMA expert GEMM (both stages) ----------------
template<int KD, int MTILES, bool STAGE2>
__global__ __launch_bounds__(256) void expert_gemm_kernel(
    const unsigned short* __restrict__ Wt,
    const unsigned short* __restrict__ Bsrc,
    const float* __restrict__ bias,
    const int* __restrict__ counts, const int* __restrict__ offsets,
    const int* __restrict__ tok_list, const float* __restrict__ gate_list,
    unsigned short* __restrict__ Hout, float* __restrict__ out)
{
  constexpr int M = MTILES * 128;
  constexpr int LMT = (MTILES == 8) ? 3 : 2;
  const int e = blockIdx.x & 7;
  const int tmp = blockIdx.x >> 3;
  const int mtile = tmp & (MTILES - 1);
  const int ttile = tmp >> LMT;
  const int cnt = counts[e];
  if (ttile * 128 >= cnt) return;
  const int base = offsets[e] + ttile * 128;
  const int rem = cnt - ttile * 128;
  const int nvalid = rem < 128 ? rem : 128;

  __shared__ unsigned short Ws[128][64];
  __shared__ unsigned short Xs[128][64];

  const int tid = threadIdx.x;
  const int lane = tid & 63;
  const int wave = tid >> 6;
  const int wm = wave & 1, wn = wave >> 1;

  const unsigned short* wsrc[4];
  const unsigned short* bsrc[4];
#pragma unroll
  for (int i = 0; i < 4; i++) {
    const int seg = tid + i * 256;
    const int row = seg >> 3;
    const int s = seg & 7;
    const int scol = ((s ^ (row & 7)) << 3);
    wsrc[i] = Wt + ((size_t)e * M + (size_t)(mtile * 128 + row)) * KD + scol;
    const int cr = (row < nvalid) ? row : (nvalid - 1);
    const int brow = STAGE2 ? (base + cr) : tok_list[base + cr];
    bsrc[i] = Bsrc + (size_t)brow * KD + scol;
  }
  unsigned short* ws0 = &Ws[0][0];
  unsigned short* xs0 = &Xs[0][0];
  const int ldso = wave * 512;

  f32x4 acc[4][4];
#pragma unroll
  for (int mi = 0; mi < 4; mi++)
#pragma unroll
    for (int nj = 0; nj < 4; nj++)
#pragma unroll
      for (int q = 0; q < 4; q++) acc[mi][nj][q] = 0.f;

  for (int k0 = 0; k0 < KD; k0 += 64) {
#pragma unroll
    for (int i = 0; i < 4; i++) {
      gload16(wsrc[i] + k0, ws0 + ldso + i * 2048);
      gload16(bsrc[i] + k0, xs0 + ldso + i * 2048);
    }
    __syncthreads();
#pragma unroll
    for (int ks = 0; ks < 2; ks++) {
      bf16x8 a[4], b[4];
#pragma unroll
      for (int mi = 0; mi < 4; mi++) {
        const int m = wm * 64 + mi * 16 + (lane & 15);
        const int sl = ((ks * 4 + (lane >> 4)) ^ (m & 7)) << 3;
        a[mi] = *reinterpret_cast<const bf16x8*>(&Ws[m][sl]);
      }
#pragma unroll
      for (int nj = 0; nj < 4; nj++) {
        const int r = wn * 64 + nj * 16 + (lane & 15);
        const int sl = ((ks * 4 + (lane >> 4)) ^ (r & 7)) << 3;
        b[nj] = *reinterpret_cast<const bf16x8*>(&Xs[r][sl]);
      }
#pragma unroll
      for (int mi = 0; mi < 4; mi++)
#pragma unroll
        for (int nj = 0; nj < 4; nj++)
          acc[mi][nj] = __builtin_amdgcn_mfma_f32_16x16x32_bf16(a[mi], b[nj], acc[mi][nj], 0, 0, 0);
    }
    __syncthreads();
  }

  if (!STAGE2) {
#pragma unroll
    for (int mi = 0; mi < 4; mi++) {
      const int mb = mtile * 128 + wm * 64 + mi * 16 + ((lane >> 4) << 2);
      float bv[4];
#pragma unroll
      for (int j = 0; j < 4; j++) bv[j] = bias[e * M + mb + j];
#pragma unroll
      for (int nj = 0; nj < 4; nj++) {
        const int r = wn * 64 + nj * 16 + (lane & 15);
        if (r < nvalid) {
          us4 o;
#pragma unroll
          for (int j = 0; j < 4; j++)
            o[j] = f2bf(fmaxf(acc[mi][nj][j] + bv[j], 0.f));
          *reinterpret_cast<us4*>(&Hout[(size_t)(base + r) * H_DIM + mb]) = o;
        }
      }
    }
  } else {
    float bv[4][4];
    int dbs[4];
#pragma unroll
    for (int mi = 0; mi < 4; mi++) {
      dbs[mi] = mtile * 128 + wm * 64 + mi * 16 + ((lane >> 4) << 2);
#pragma unroll
      for (int j = 0; j < 4; j++) bv[mi][j] = bias[e * M + dbs[mi] + j];
    }
#pragma unroll
    for (int nj = 0; nj < 4; nj++) {
      const int r = wn * 64 + nj * 16 + (lane & 15);
      if (r >= nvalid) continue;
      const int slot = base + r;
      const int tok = tok_list[slot];
      const float g = gate_list[slot];
      float* orow = out + (size_t)tok * D_DIM;
#pragma unroll
      for (int mi = 0; mi < 4; mi++)
#pragma unroll
        for (int j = 0; j < 4; j++)
          atomicAdd(&orow[dbs[mi] + j], (acc[mi][nj][j] + bv[mi][j]) * g);
    }
  }
}

// ---------------- launcher ----------------
extern "C" void kernel_launch(void* const* d_in, const int* in_sizes, int n_in,
                              void* d_out, int out_size, void* d_ws, size_t ws_size,
                              hipStream_t stream)
{
  const float* x  = (const float*)d_in[0];
  const float* Wg = (const float*)d_in[1];
  const float* W1 = (const float*)d_in[2];
  const float* b1 = (const float*)d_in[3];
  const float* W2 = (const float*)d_in[4];
  const float* b2 = (const float*)d_in[5];
  float* out = (float*)d_out;

  char* ws = (char*)d_ws;
  int*   counts     = (int*)(ws + 0);
  float* importance = (float*)(ws + 32);
  int*   offsets    = (int*)(ws + 64);
  int*   top_e      = (int*)(ws + 128);
  float* top_p      = (float*)(ws + 128 + 65536);
  int*   tok_list   = (int*)(ws + 128 + 131072);
  float* gate_list  = (float*)(ws + 128 + 196608);
  int*   hist       = (int*)(ws + 262400);
  float* impp       = (float*)(ws + 264448);
  int*   bb         = (int*)(ws + 266496);
  unsigned short* XB   = (unsigned short*)(ws + (1ull << 20));
  unsigned short* W1T  = (unsigned short*)(ws + (9ull << 20));
  unsigned short* W2T  = (unsigned short*)(ws + (17ull << 20));
  unsigned short* HBUF = (unsigned short*)(ws + (25ull << 20));

  hipMemsetAsync(d_out, 0, (size_t)T_TOK * D_DIM * sizeof(float), stream);

  cvt_x_kernel<<<2048, 256, 0, stream>>>(x, XB);
  wtrans_kernel<<<8192, 256, 0, stream>>>(W1, W2, W1T, W2T);
  gating_kernel<<<T_TOK / 4, 256, 0, stream>>>(x, Wg, top_e, top_p);
  hist_kernel<<<NHB, 256, 0, stream>>>(top_e, top_p, hist, impp);
  finalize_kernel<<<1, 64, 0, stream>>>(hist, impp, counts, importance, offsets, bb,
                                        out + (size_t)T_TOK * D_DIM);
  scatter_kernel<<<NHB, 256, 0, stream>>>(top_e, top_p, bb, tok_list, gate_list);
  // stage 1: H = relu(x @ W1 + b1)   (M=1024, K=512)
  expert_gemm_kernel<512, 8, false><<<8 * 8 * 64, 256, 0, stream>>>(
      W1T, XB, b1, counts, offsets, tok_list, gate_list, HBUF, nullptr);
  // stage 2: out += gate * (H @ W2 + b2)   (M=512, K=1024)
  expert_gemm_kernel<1024, 4, true><<<8 * 4 * 64, 256, 0, stream>>>(
      W2T, HBUF, b2, counts, offsets, tok_list, gate_list, nullptr, out);
}

// Round 5
// 208.429 us; speedup vs baseline: 9.5659x; 1.4511x over previous
//
#include <hip/hip_runtime.h>
#include <math.h>

#define T_TOK 8192
#define D_DIM 512
#define H_DIM 1024
#define NE    8
#define NHB   64    // histogram/scatter blocks (64 x 256 threads = 16384 entries)

typedef __attribute__((ext_vector_type(8))) short bf16x8;
typedef __attribute__((ext_vector_type(4))) float f32x4;
typedef __attribute__((ext_vector_type(4))) unsigned short us4;
typedef __attribute__((ext_vector_type(8))) unsigned short us8;

// ---------------- workspace layout (bytes) ----------------
// 0       counts[8] | 32 importance[8] | 64 offsets[8]
// 128     top_e[16384] int      (64 KB)
// 65664   top_p[16384] float    (64 KB)
// 131200  tok_list[16384] int
// 196736  gate_list[16384] float
// 262400  hist[64][8] int   | 264448 impp[64][8] float | 266496 bb[64][8] int
// 268544  inv_slot[16384] int  (64 KB)
// 1 MB    XB   bf16 [8192][512]      8 MB   (dead after stage1)
// 9 MB    W1T  bf16 [8][1024][512]   8 MB   (dead after stage1)
// 1 MB    EO   bf16 [16384][512]    16 MB   (aliases XB+W1T, written by stage2)
// 17 MB   W2T  bf16 [8][512][1024]   8 MB
// 25 MB   HBUF bf16 [16384][1024]   32 MB

__device__ __forceinline__ unsigned short f2bf(float f) {
  union { float f; unsigned int u; } v; v.f = f;
  const unsigned int u = v.u;
  return (unsigned short)((u + 0x7fffu + ((u >> 16) & 1u)) >> 16);  // RNE
}

__device__ __forceinline__ float bf2f(unsigned short b) {
  union { unsigned int u; float f; } v; v.u = ((unsigned int)b) << 16;
  return v.f;
}

__device__ __forceinline__ void gload16(const void* g, void* l) {
  __builtin_amdgcn_global_load_lds(
      (const __attribute__((address_space(1))) void*)g,
      (__attribute__((address_space(3))) void*)l, 16, 0, 0);
}

// ---------------- x -> bf16 ----------------
__global__ __launch_bounds__(256) void cvt_x_kernel(const float* __restrict__ x,
                                                    unsigned short* __restrict__ xb) {
  const int i = (blockIdx.x * 256 + threadIdx.x) * 8;
  const float4 a = *reinterpret_cast<const float4*>(&x[i]);
  const float4 b = *reinterpret_cast<const float4*>(&x[i + 4]);
  us8 o;
  o[0] = f2bf(a.x); o[1] = f2bf(a.y); o[2] = f2bf(a.z); o[3] = f2bf(a.w);
  o[4] = f2bf(b.x); o[5] = f2bf(b.y); o[6] = f2bf(b.z); o[7] = f2bf(b.w);
  *reinterpret_cast<us8*>(&xb[i]) = o;
}

// ---------------- W1/W2 -> bf16, transposed per expert ----------------
__global__ __launch_bounds__(256) void wtrans_kernel(
    const float* __restrict__ W1, const float* __restrict__ W2,
    unsigned short* __restrict__ W1T, unsigned short* __restrict__ W2T) {
  __shared__ unsigned short lds[32][36];
  int bid = blockIdx.x;
  const float* src; unsigned short* dst; int R, C, lc;
  if (bid < 4096) { src = W1; dst = W1T; R = D_DIM; C = H_DIM; lc = 5; }
  else { bid -= 4096; src = W2; dst = W2T; R = H_DIM; C = D_DIM; lc = 4; }
  const int e = bid >> 9;
  const int rem = bid & 511;
  const int rt = rem >> lc;
  const int ct = rem & ((C >> 5) - 1);
  const size_t ebase = (size_t)e * R * C;
  const int tid = threadIdx.x;
  {
    const int r = tid >> 3, c0 = (tid & 7) * 4;
    const float4 v = *reinterpret_cast<const float4*>(
        &src[ebase + (size_t)(rt * 32 + r) * C + ct * 32 + c0]);
    lds[r][c0 + 0] = f2bf(v.x); lds[r][c0 + 1] = f2bf(v.y);
    lds[r][c0 + 2] = f2bf(v.z); lds[r][c0 + 3] = f2bf(v.w);
  }
  __syncthreads();
  {
    const int c = tid >> 3, r0 = (tid & 7) * 4;
    us4 o;
    o[0] = lds[r0 + 0][c]; o[1] = lds[r0 + 1][c];
    o[2] = lds[r0 + 2][c]; o[3] = lds[r0 + 3][c];
    *reinterpret_cast<us4*>(&dst[ebase + (size_t)(ct * 32 + c) * R + rt * 32 + r0]) = o;
  }
}

// ---------------- gating: logits, top-2, softmax (NO global atomics) ----------------
__global__ __launch_bounds__(256) void gating_kernel(
    const float* __restrict__ x, const float* __restrict__ Wg,
    int* __restrict__ top_e, float* __restrict__ top_p)
{
  __shared__ float wgs[NE][D_DIM];
  const int tid = threadIdx.x;
  for (int i = tid; i < D_DIM * NE; i += 256)
    wgs[i & 7][i >> 3] = Wg[i];
  __syncthreads();

  const int lane = tid & 63;
  const int wave = tid >> 6;
  const int t = blockIdx.x * 4 + wave;

  float acc[NE];
#pragma unroll
  for (int e = 0; e < NE; e++) acc[e] = 0.f;
#pragma unroll
  for (int j = 0; j < 8; j++) {
    const int d = lane + j * 64;
    const float xv = x[(size_t)t * D_DIM + d];
#pragma unroll
    for (int e = 0; e < NE; e++) acc[e] += xv * wgs[e][d];
  }
#pragma unroll
  for (int e = 0; e < NE; e++) {
#pragma unroll
    for (int m = 32; m > 0; m >>= 1) acc[e] += __shfl_xor(acc[e], m);
  }

  if (lane == 0) {
    int i0 = 0; float v0 = acc[0];
#pragma unroll
    for (int e = 1; e < NE; e++) if (acc[e] > v0) { v0 = acc[e]; i0 = e; }
    int i1 = -1; float v1 = -3.4e38f;
#pragma unroll
    for (int e = 0; e < NE; e++) if (e != i0 && acc[e] > v1) { v1 = acc[e]; i1 = e; }

    const float ex = __expf(v1 - v0);
    const float inv = 1.f / (1.f + ex);
    top_e[t * 2 + 0] = i0; top_e[t * 2 + 1] = i1;
    top_p[t * 2 + 0] = inv; top_p[t * 2 + 1] = ex * inv;
  }
}

// ---------------- per-block histogram + importance partials (LDS atomics only) ----------------
__global__ __launch_bounds__(256) void hist_kernel(
    const int* __restrict__ top_e, const float* __restrict__ top_p,
    int* __restrict__ hist, float* __restrict__ impp)
{
  __shared__ int   h[NE];
  __shared__ float im[NE];
  const int tid = threadIdx.x;
  if (tid < NE) { h[tid] = 0; im[tid] = 0.f; }
  __syncthreads();
  const int i = blockIdx.x * 256 + tid;
  const int e = top_e[i];
  atomicAdd(&h[e], 1);
  atomicAdd(&im[e], top_p[i]);
  __syncthreads();
  if (tid < NE) {
    hist[blockIdx.x * NE + tid] = h[tid];
    impp[blockIdx.x * NE + tid] = im[tid];
  }
}

// ---------------- finalize: counts/offsets/block-bases + losses ----------------
__global__ void finalize_kernel(const int* __restrict__ hist,
                                const float* __restrict__ impp,
                                int* __restrict__ counts, float* __restrict__ importance,
                                int* __restrict__ offsets, int* __restrict__ bb,
                                float* __restrict__ out_tail)
{
  __shared__ int   cnt_s[NE];
  __shared__ float imp_s[NE];
  __shared__ int   off_s[NE];
  const int tid = threadIdx.x;
  if (tid < NE) {
    int c = 0; float s = 0.f;
    for (int b = 0; b < NHB; b++) { c += hist[b * NE + tid]; s += impp[b * NE + tid]; }
    cnt_s[tid] = c; imp_s[tid] = s;
    counts[tid] = c; importance[tid] = s;
  }
  __syncthreads();
  if (tid == 0) {
    int off = 0;
    for (int e = 0; e < NE; e++) { off_s[e] = off; offsets[e] = off; off += cnt_s[e]; }
    float mi = 0.f, ml = 0.f;
    for (int e = 0; e < NE; e++) { mi += imp_s[e]; ml += (float)cnt_s[e]; }
    mi *= (1.f / NE); ml *= (1.f / NE);
    float vi = 0.f, vl = 0.f;
    for (int e = 0; e < NE; e++) {
      const float di = imp_s[e] - mi; vi += di * di;
      const float dl = (float)cnt_s[e] - ml; vl += dl * dl;
    }
    vi *= (1.f / (NE - 1)); vl *= (1.f / (NE - 1));   // ddof=1
    out_tail[0] = vi / (mi * mi + 1e-10f);
    out_tail[1] = vl / (ml * ml + 1e-10f);
  }
  __syncthreads();
  if (tid < NE) {
    int run = off_s[tid];
    for (int b = 0; b < NHB; b++) { bb[b * NE + tid] = run; run += hist[b * NE + tid]; }
  }
}

// ---------------- scatter: slot assignment via LDS cursors + inverse map ----------------
__global__ __launch_bounds__(256) void scatter_kernel(
    const int* __restrict__ top_e, const float* __restrict__ top_p,
    const int* __restrict__ bb,
    int* __restrict__ tok_list, int* __restrict__ inv_slot)
{
  __shared__ int cur[NE];
  const int tid = threadIdx.x;
  if (tid < NE) cur[tid] = bb[blockIdx.x * NE + tid];
  __syncthreads();
  const int i = blockIdx.x * 256 + tid;
  const int e = top_e[i];
  const int pos = atomicAdd(&cur[e], 1);   // LDS atomic: intra-block only
  tok_list[pos] = i >> 1;
  inv_slot[i] = pos;
}

// ---------------- MFMA expert GEMM (both stages) ----------------
// STAGE2=false: Hout[slot][h] = relu(C + b1)  (OD=H_DIM)
// STAGE2=true : Hout[slot][d] =      C + b2   (OD=D_DIM, un-gated expert output)
template<int KD, int MTILES, bool STAGE2>
__global__ __launch_bounds__(256) void expert_gemm_kernel(
    const unsigned short* __restrict__ Wt,
    const unsigned short* __restrict__ Bsrc,
    const float* __restrict__ bias,
    const int* __restrict__ counts, const int* __restrict__ offsets,
    const int* __restrict__ tok_list,
    unsigned short* __restrict__ Hout)
{
  constexpr int M = MTILES * 128;
  constexpr int LMT = (MTILES == 8) ? 3 : 2;
  constexpr int OD = STAGE2 ? D_DIM : H_DIM;
  const int e = blockIdx.x & 7;
  const int tmp = blockIdx.x >> 3;
  const int mtile = tmp & (MTILES - 1);
  const int ttile = tmp >> LMT;
  const int cnt = counts[e];
  if (ttile * 128 >= cnt) return;
  const int base = offsets[e] + ttile * 128;
  const int rem = cnt - ttile * 128;
  const int nvalid = rem < 128 ? rem : 128;

  __shared__ unsigned short Ws[128][64];
  __shared__ unsigned short Xs[128][64];

  const int tid = threadIdx.x;
  const int lane = tid & 63;
  const int wave = tid >> 6;
  const int wm = wave & 1, wn = wave >> 1;

  const unsigned short* wsrc[4];
  const unsigned short* bsrc[4];
#pragma unroll
  for (int i = 0; i < 4; i++) {
    const int seg = tid + i * 256;
    const int row = seg >> 3;
    const int s = seg & 7;
    const int scol = ((s ^ (row & 7)) << 3);
    wsrc[i] = Wt + ((size_t)e * M + (size_t)(mtile * 128 + row)) * KD + scol;
    const int cr = (row < nvalid) ? row : (nvalid - 1);
    const int brow = STAGE2 ? (base + cr) : tok_list[base + cr];
    bsrc[i] = Bsrc + (size_t)brow * KD + scol;
  }
  unsigned short* ws0 = &Ws[0][0];
  unsigned short* xs0 = &Xs[0][0];
  const int ldso = wave * 512;

  f32x4 acc[4][4];
#pragma unroll
  for (int mi = 0; mi < 4; mi++)
#pragma unroll
    for (int nj = 0; nj < 4; nj++)
#pragma unroll
      for (int q = 0; q < 4; q++) acc[mi][nj][q] = 0.f;

  for (int k0 = 0; k0 < KD; k0 += 64) {
#pragma unroll
    for (int i = 0; i < 4; i++) {
      gload16(wsrc[i] + k0, ws0 + ldso + i * 2048);
      gload16(bsrc[i] + k0, xs0 + ldso + i * 2048);
    }
    __syncthreads();
#pragma unroll
    for (int ks = 0; ks < 2; ks++) {
      bf16x8 a[4], b[4];
#pragma unroll
      for (int mi = 0; mi < 4; mi++) {
        const int m = wm * 64 + mi * 16 + (lane & 15);
        const int sl = ((ks * 4 + (lane >> 4)) ^ (m & 7)) << 3;
        a[mi] = *reinterpret_cast<const bf16x8*>(&Ws[m][sl]);
      }
#pragma unroll
      for (int nj = 0; nj < 4; nj++) {
        const int r = wn * 64 + nj * 16 + (lane & 15);
        const int sl = ((ks * 4 + (lane >> 4)) ^ (r & 7)) << 3;
        b[nj] = *reinterpret_cast<const bf16x8*>(&Xs[r][sl]);
      }
#pragma unroll
      for (int mi = 0; mi < 4; mi++)
#pragma unroll
        for (int nj = 0; nj < 4; nj++)
          acc[mi][nj] = __builtin_amdgcn_mfma_f32_16x16x32_bf16(a[mi], b[nj], acc[mi][nj], 0, 0, 0);
    }
    __syncthreads();
  }

  // epilogue: m_loc = wm*64+mi*16+(lane>>4)*4+j (weight dim), n_loc = wn*64+nj*16+(lane&15) (slot)
#pragma unroll
  for (int mi = 0; mi < 4; mi++) {
    const int mb = mtile * 128 + wm * 64 + mi * 16 + ((lane >> 4) << 2);
    float bv[4];
#pragma unroll
    for (int j = 0; j < 4; j++) bv[j] = bias[e * M + mb + j];
#pragma unroll
    for (int nj = 0; nj < 4; nj++) {
      const int r = wn * 64 + nj * 16 + (lane & 15);
      if (r < nvalid) {
        us4 o;
#pragma unroll
        for (int j = 0; j < 4; j++) {
          const float v = acc[mi][nj][j] + bv[j];
          o[j] = f2bf(STAGE2 ? v : fmaxf(v, 0.f));
        }
        *reinterpret_cast<us4*>(&Hout[(size_t)(base + r) * OD + mb]) = o;
      }
    }
  }
}

// ---------------- combine: out[t] = p0*EO[s0] + p1*EO[s1] ----------------
__global__ __launch_bounds__(256) void combine_kernel(
    const unsigned short* __restrict__ EO,
    const int* __restrict__ inv_slot, const float* __restrict__ top_p,
    float* __restrict__ out)
{
  const int idx = blockIdx.x * 256 + threadIdx.x;
  const int t  = idx >> 6;            // 64 threads per token (512/8)
  const int d0 = (idx & 63) * 8;
  const int s0 = inv_slot[t * 2 + 0];
  const int s1 = inv_slot[t * 2 + 1];
  const float p0 = top_p[t * 2 + 0];
  const float p1 = top_p[t * 2 + 1];
  const us8 a = *reinterpret_cast<const us8*>(&EO[(size_t)s0 * D_DIM + d0]);
  const us8 b = *reinterpret_cast<const us8*>(&EO[(size_t)s1 * D_DIM + d0]);
  float4 o0, o1;
  o0.x = p0 * bf2f(a[0]) + p1 * bf2f(b[0]);
  o0.y = p0 * bf2f(a[1]) + p1 * bf2f(b[1]);
  o0.z = p0 * bf2f(a[2]) + p1 * bf2f(b[2]);
  o0.w = p0 * bf2f(a[3]) + p1 * bf2f(b[3]);
  o1.x = p0 * bf2f(a[4]) + p1 * bf2f(b[4]);
  o1.y = p0 * bf2f(a[5]) + p1 * bf2f(b[5]);
  o1.z = p0 * bf2f(a[6]) + p1 * bf2f(b[6]);
  o1.w = p0 * bf2f(a[7]) + p1 * bf2f(b[7]);
  float* op = &out[(size_t)t * D_DIM + d0];
  *reinterpret_cast<float4*>(op)     = o0;
  *reinterpret_cast<float4*>(op + 4) = o1;
}

// ---------------- launcher ----------------
extern "C" void kernel_launch(void* const* d_in, const int* in_sizes, int n_in,
                              void* d_out, int out_size, void* d_ws, size_t ws_size,
                              hipStream_t stream)
{
  const float* x  = (const float*)d_in[0];
  const float* Wg = (const float*)d_in[1];
  const float* W1 = (const float*)d_in[2];
  const float* b1 = (const float*)d_in[3];
  const float* W2 = (const float*)d_in[4];
  const float* b2 = (const float*)d_in[5];
  float* out = (float*)d_out;

  char* ws = (char*)d_ws;
  int*   counts     = (int*)(ws + 0);
  float* importance = (float*)(ws + 32);
  int*   offsets    = (int*)(ws + 64);
  int*   top_e      = (int*)(ws + 128);
  float* top_p      = (float*)(ws + 128 + 65536);
  int*   tok_list   = (int*)(ws + 128 + 131072);
  int*   hist       = (int*)(ws + 262400);
  float* impp       = (float*)(ws + 264448);
  int*   bb         = (int*)(ws + 266496);
  int*   inv_slot   = (int*)(ws + 268544);
  unsigned short* XB   = (unsigned short*)(ws + (1ull << 20));
  unsigned short* W1T  = (unsigned short*)(ws + (9ull << 20));
  unsigned short* W2T  = (unsigned short*)(ws + (17ull << 20));
  unsigned short* HBUF = (unsigned short*)(ws + (25ull << 20));
  unsigned short* EO   = (unsigned short*)(ws + (1ull << 20));  // aliases XB+W1T (dead after stage1)

  cvt_x_kernel<<<2048, 256, 0, stream>>>(x, XB);
  wtrans_kernel<<<8192, 256, 0, stream>>>(W1, W2, W1T, W2T);
  gating_kernel<<<T_TOK / 4, 256, 0, stream>>>(x, Wg, top_e, top_p);
  hist_kernel<<<NHB, 256, 0, stream>>>(top_e, top_p, hist, impp);
  finalize_kernel<<<1, 64, 0, stream>>>(hist, impp, counts, importance, offsets, bb,
                                        out + (size_t)T_TOK * D_DIM);
  scatter_kernel<<<NHB, 256, 0, stream>>>(top_e, top_p, bb, tok_list, inv_slot);
  // stage 1: HBUF = relu(x @ W1 + b1)   (M=1024, K=512)
  expert_gemm_kernel<512, 8, false><<<8 * 8 * 64, 256, 0, stream>>>(
      W1T, XB, b1, counts, offsets, tok_list, HBUF);
  // stage 2: EO = HBUF @ W2 + b2        (M=512, K=1024)
  expert_gemm_kernel<1024, 4, true><<<8 * 4 * 64, 256, 0, stream>>>(
      W2T, HBUF, b2, counts, offsets, tok_list, EO);
  // combine: out[t] = p0*EO[s0] + p1*EO[s1]
  combine_kernel<<<T_TOK * D_DIM / (256 * 8), 256, 0, stream>>>(EO, inv_slot, top_p, out);
}